// Round 5
// baseline (265.613 us; speedup 1.0000x reference)
//
#include <hip/hip_runtime.h>
#include <hip/hip_bf16.h>
#include <math.h>

#define B_ 16
#define D_ 512
#define N_ 4096   // H*W
#define K_ 64

typedef __attribute__((ext_vector_type(8))) short bfrag;   // 8 bf16 = 4 VGPRs
typedef __attribute__((ext_vector_type(4))) float f32x4;

static __device__ __forceinline__ float bf2f(unsigned short u) {
    return __uint_as_float(((unsigned)u) << 16);
}
static __device__ __forceinline__ unsigned short f2bf(float v) {
    __hip_bfloat16 h = __float2bfloat16(v);   // RNE
    union { __hip_bfloat16 h; unsigned short u; } cv; cv.h = h; return cv.u;
}
static __device__ __forceinline__ void split3(float v, unsigned short& h,
                                              unsigned short& m, unsigned short& l) {
    h = f2bf(v); float r1 = v - bf2f(h);
    m = f2bf(r1); float r2 = r1 - bf2f(m);
    l = f2bf(r2);
}
static __device__ __forceinline__ void split2(float v, unsigned short& h,
                                              unsigned short& l) {
    h = f2bf(v); l = f2bf(v - bf2f(h));
}
#define MFMA(a, b, c) __builtin_amdgcn_mfma_f32_16x16x32_bf16((a), (b), (c), 0, 0, 0)

// ---------------------------------------------------------------------------
// K0: pre-split conv_w into 3 bf16 limb planes [lv][64][512] (192 KB total).
// ---------------------------------------------------------------------------
__global__ __launch_bounds__(256) void k_prep(
    const float* __restrict__ conv_w, unsigned short* __restrict__ cwL)
{
    const int i = blockIdx.x * 256 + threadIdx.x;   // 8192 threads x 4 elems
    const float4 v = *(const float4*)&conv_w[i * 4];
    const float vv[4] = {v.x, v.y, v.z, v.w};
    unsigned short h[4], m[4], l[4];
    #pragma unroll
    for (int j = 0; j < 4; ++j) split3(vv[j], h[j], m[j], l[j]);
    *(ushort4*)&cwL[0 * (K_ * D_) + i * 4] = make_ushort4(h[0], h[1], h[2], h[3]);
    *(ushort4*)&cwL[1 * (K_ * D_) + i * 4] = make_ushort4(m[0], m[1], m[2], m[3]);
    *(ushort4*)&cwL[2 * (K_ * D_) + i * 4] = make_ushort4(l[0], l[1], l[2], l[3]);
}

// ---------------------------------------------------------------------------
// K1: logits via 3-way-split bf16 MFMA + softmax + w limbs + fused wsum.
// 64-n chunk per block (grid 1024) for 3-4 blocks/CU occupancy. No register
// prefetch (round-4 experiment regressed: VGPR pressure, no real overlap).
// ---------------------------------------------------------------------------
__global__ __launch_bounds__(256) void k_logits_softmax(
    const float* __restrict__ x, const unsigned short* __restrict__ cwL,
    const float* __restrict__ conv_b,
    unsigned short* __restrict__ wh, unsigned short* __restrict__ wl,
    float* __restrict__ wsumbuf)
{
    const int b   = blockIdx.x >> 6;
    const int n0  = (blockIdx.x & 63) * 64;
    const int tid  = threadIdx.x;
    const int w    = tid >> 6;
    const int lane = tid & 63;
    const int q = lane >> 4;
    const int c = lane & 15;
    const int ktb = (w & 1) * 32;    // k-half per wave
    const int ntb = (w >> 1) * 32;   // n-half per wave

    __shared__ unsigned short cws[3][64][40];   // [lvl][k][d]
    __shared__ unsigned short xs[3][64][40];    // [lvl][n][d]
    __shared__ float redm[2][64];
    __shared__ float reds[2][64];

    f32x4 acc[2][2];
    #pragma unroll
    for (int kt = 0; kt < 2; ++kt)
        #pragma unroll
        for (int nt = 0; nt < 2; ++nt) acc[kt][nt] = (f32x4){0.f, 0.f, 0.f, 0.f};

    const float* xb = x + (size_t)b * D_ * N_ + n0;

    const int ks = tid >> 2;            // cw row
    const int d8 = (tid & 3) * 8;       // cw d-offset

    for (int d0 = 0; d0 < D_; d0 += 32) {
        // stage cw limbs: raw uint4 copies from pre-split planes
        #pragma unroll
        for (int lv = 0; lv < 3; ++lv)
            *(uint4*)&cws[lv][ks][d8] =
                *(const uint4*)&cwL[lv * (K_ * D_) + ks * D_ + d0 + d8];
        // stage x 32d x 64n transposed -> xs[n][d], split3
        #pragma unroll
        for (int i = 0; i < 2; ++i) {
            const int s   = i * 256 + tid;
            const int xn  = s & 63;
            const int dg4 = (s >> 6) * 4;
            unsigned short h[4], m[4], l[4];
            #pragma unroll
            for (int r = 0; r < 4; ++r) {
                const float v = xb[(size_t)(d0 + dg4 + r) * N_ + xn];
                split3(v, h[r], m[r], l[r]);
            }
            *(ushort4*)&xs[0][xn][dg4] = make_ushort4(h[0], h[1], h[2], h[3]);
            *(ushort4*)&xs[1][xn][dg4] = make_ushort4(m[0], m[1], m[2], m[3]);
            *(ushort4*)&xs[2][xn][dg4] = make_ushort4(l[0], l[1], l[2], l[3]);
        }
        __syncthreads();

        bfrag af[2][3];
        #pragma unroll
        for (int kt = 0; kt < 2; ++kt)
            #pragma unroll
            for (int lv = 0; lv < 3; ++lv)
                af[kt][lv] = *(const bfrag*)&cws[lv][ktb + kt * 16 + c][q * 8];
        #pragma unroll
        for (int nt = 0; nt < 2; ++nt) {
            bfrag bf[3];
            #pragma unroll
            for (int lv = 0; lv < 3; ++lv)
                bf[lv] = *(const bfrag*)&xs[lv][ntb + nt * 16 + c][q * 8];
            #pragma unroll
            for (int kt = 0; kt < 2; ++kt) {
                f32x4 a = acc[kt][nt];
                a = MFMA(af[kt][0], bf[0], a);   // hh
                a = MFMA(af[kt][0], bf[1], a);   // hm
                a = MFMA(af[kt][1], bf[0], a);   // mh
                a = MFMA(af[kt][1], bf[1], a);   // mm
                a = MFMA(af[kt][0], bf[2], a);   // hl
                a = MFMA(af[kt][2], bf[0], a);   // lh
                acc[kt][nt] = a;
            }
        }
        __syncthreads();
    }

    // ---- bias + cross-wave softmax (lane owns k=ktb+kt*16+q*4+r, n=ntb+nt*16+c)
    #pragma unroll
    for (int kt = 0; kt < 2; ++kt)
        #pragma unroll
        for (int r = 0; r < 4; ++r) {
            const float bias = conv_b[ktb + kt * 16 + q * 4 + r];
            #pragma unroll
            for (int nt = 0; nt < 2; ++nt) acc[kt][nt][r] += bias;
        }

    float mloc[2];
    #pragma unroll
    for (int nt = 0; nt < 2; ++nt) {
        float m = acc[0][nt][0];
        #pragma unroll
        for (int kt = 0; kt < 2; ++kt)
            #pragma unroll
            for (int r = 0; r < 4; ++r) m = fmaxf(m, acc[kt][nt][r]);
        m = fmaxf(m, __shfl_xor(m, 16));
        m = fmaxf(m, __shfl_xor(m, 32));
        mloc[nt] = m;
    }
    if (q == 0)
        #pragma unroll
        for (int nt = 0; nt < 2; ++nt) redm[w & 1][ntb + nt * 16 + c] = mloc[nt];
    __syncthreads();
    float mall[2];
    #pragma unroll
    for (int nt = 0; nt < 2; ++nt)
        mall[nt] = fmaxf(redm[0][ntb + nt * 16 + c], redm[1][ntb + nt * 16 + c]);

    float sloc[2] = {0.f, 0.f};
    #pragma unroll
    for (int nt = 0; nt < 2; ++nt) {
        #pragma unroll
        for (int kt = 0; kt < 2; ++kt)
            #pragma unroll
            for (int r = 0; r < 4; ++r) {
                const float e = __expf(acc[kt][nt][r] - mall[nt]);
                acc[kt][nt][r] = e;
                sloc[nt] += e;
            }
        sloc[nt] += __shfl_xor(sloc[nt], 16);
        sloc[nt] += __shfl_xor(sloc[nt], 32);
    }
    if (q == 0)
        #pragma unroll
        for (int nt = 0; nt < 2; ++nt) reds[w & 1][ntb + nt * 16 + c] = sloc[nt];
    __syncthreads();

    float wacc[2][4] = {{0.f, 0.f, 0.f, 0.f}, {0.f, 0.f, 0.f, 0.f}};
    #pragma unroll
    for (int nt = 0; nt < 2; ++nt) {
        const float inv = 1.0f / (reds[0][ntb + nt * 16 + c] + reds[1][ntb + nt * 16 + c]);
        #pragma unroll
        for (int kt = 0; kt < 2; ++kt)
            #pragma unroll
            for (int r = 0; r < 4; ++r) {
                const float v = acc[kt][nt][r] * inv;
                unsigned short hi, lo;
                split2(v, hi, lo);
                const size_t idx = ((size_t)b * K_ + ktb + kt * 16 + q * 4 + r) * N_
                                 + n0 + ntb + nt * 16 + c;
                wh[idx] = hi;
                wl[idx] = lo;
                wacc[kt][r] += v;
            }
    }
    // fused wsum: reduce over the 16 c-lanes, then one atomic per (k, wave)
    #pragma unroll
    for (int msk = 1; msk < 16; msk <<= 1)
        #pragma unroll
        for (int kt = 0; kt < 2; ++kt)
            #pragma unroll
            for (int r = 0; r < 4; ++r)
                wacc[kt][r] += __shfl_xor(wacc[kt][r], msk);
    if (c == 0)
        #pragma unroll
        for (int kt = 0; kt < 2; ++kt)
            #pragma unroll
            for (int r = 0; r < 4; ++r)
                atomicAdd(&wsumbuf[b * K_ + ktb + kt * 16 + q * 4 + r], wacc[kt][r]);
}

// ---------------------------------------------------------------------------
// K2: vlad += w . x^T via 2-way-split bf16 MFMA. nc=16 x dc=4 (grid 1024)
// for ~3 blocks/CU. No register prefetch (see round-4 post-mortem).
// ---------------------------------------------------------------------------
__global__ __launch_bounds__(256) void k_wx(
    const float* __restrict__ x, const unsigned short* __restrict__ wh,
    const unsigned short* __restrict__ wl, float* __restrict__ vlad)
{
    const int nc = blockIdx.x & 15;
    const int dc = (blockIdx.x >> 4) & 3;
    const int b  = blockIdx.x >> 6;
    const int tid  = threadIdx.x;
    const int w    = tid >> 6;
    const int lane = tid & 63;
    const int q = lane >> 4;
    const int c = lane & 15;
    const int ktb = (w & 1) * 32;
    const int dtb = (w >> 1) * 64;

    __shared__ unsigned short ws2[2][64][40];    // [lvl][k][n]
    __shared__ unsigned short xs2[2][128][40];   // [lvl][d][n]

    f32x4 acc[2][4];
    #pragma unroll
    for (int kt = 0; kt < 2; ++kt)
        #pragma unroll
        for (int dt = 0; dt < 4; ++dt) acc[kt][dt] = (f32x4){0.f, 0.f, 0.f, 0.f};

    const float* xb = x + (size_t)b * D_ * N_ + (size_t)dc * 128 * N_;
    const unsigned short* whb = wh + (size_t)b * K_ * N_;
    const unsigned short* wlb = wl + (size_t)b * K_ * N_;

    const int wk = tid >> 2;            // w row
    const int wn = (tid & 3) * 8;       // w n-offset
    const int xd = tid >> 3;            // x row (i adds 32i)
    const int xn = (tid & 7) * 4;       // x n-offset

    const int nbase = nc * 256;
    for (int n0 = nbase; n0 < nbase + 256; n0 += 32) {
        *(uint4*)&ws2[0][wk][wn] = *(const uint4*)&whb[(size_t)wk * N_ + n0 + wn];
        *(uint4*)&ws2[1][wk][wn] = *(const uint4*)&wlb[(size_t)wk * N_ + n0 + wn];
        #pragma unroll
        for (int i = 0; i < 4; ++i) {
            const float4 v = *(const float4*)&xb[(size_t)(i * 32 + xd) * N_ + n0 + xn];
            const float vv[4] = {v.x, v.y, v.z, v.w};
            unsigned short h[4], l[4];
            #pragma unroll
            for (int j = 0; j < 4; ++j) split2(vv[j], h[j], l[j]);
            *(ushort4*)&xs2[0][i * 32 + xd][xn] = make_ushort4(h[0], h[1], h[2], h[3]);
            *(ushort4*)&xs2[1][i * 32 + xd][xn] = make_ushort4(l[0], l[1], l[2], l[3]);
        }
        __syncthreads();

        bfrag afh[2], afl[2];
        #pragma unroll
        for (int kt = 0; kt < 2; ++kt) {
            afh[kt] = *(const bfrag*)&ws2[0][ktb + kt * 16 + c][q * 8];
            afl[kt] = *(const bfrag*)&ws2[1][ktb + kt * 16 + c][q * 8];
        }
        #pragma unroll
        for (int dt = 0; dt < 4; ++dt) {
            const bfrag bh = *(const bfrag*)&xs2[0][dtb + dt * 16 + c][q * 8];
            const bfrag bl = *(const bfrag*)&xs2[1][dtb + dt * 16 + c][q * 8];
            #pragma unroll
            for (int kt = 0; kt < 2; ++kt) {
                f32x4 a = acc[kt][dt];
                a = MFMA(afh[kt], bh, a);
                a = MFMA(afh[kt], bl, a);
                a = MFMA(afl[kt], bh, a);
                acc[kt][dt] = a;
            }
        }
        __syncthreads();
    }

    #pragma unroll
    for (int kt = 0; kt < 2; ++kt)
        #pragma unroll
        for (int dt = 0; dt < 4; ++dt)
            #pragma unroll
            for (int r = 0; r < 4; ++r) {
                const int k = ktb + kt * 16 + q * 4 + r;
                const int d = dc * 128 + dtb + dt * 16 + c;
                atomicAdd(&vlad[((size_t)b * K_ + k) * D_ + d], acc[kt][dt][r]);
            }
}

// ---------------------------------------------------------------------------
// K3: v = vlad - wsum*c; row L2-norm; global norm = /8.  (wsum precomputed)
// ---------------------------------------------------------------------------
__global__ __launch_bounds__(256) void k_norm(
    const float* __restrict__ wsumbuf, const float* __restrict__ vlad,
    const float* __restrict__ centers, float* __restrict__ out)
{
    const int b = blockIdx.x >> 6;
    const int k = blockIdx.x & 63;
    const int tid = threadIdx.x;

    const float wsum = wsumbuf[b * K_ + k];

    const float* vr = vlad + ((size_t)b * K_ + k) * D_;
    const float* cr = centers + k * D_;
    const float v0 = vr[tid]       - wsum * cr[tid];
    const float v1 = vr[tid + 256] - wsum * cr[tid + 256];

    float ss = v0 * v0 + v1 * v1;
    __shared__ float red2[4];
    #pragma unroll
    for (int off = 32; off > 0; off >>= 1) ss += __shfl_down(ss, off, 64);
    if ((tid & 63) == 0) red2[tid >> 6] = ss;
    __syncthreads();
    const float nrm = sqrtf(red2[0] + red2[1] + red2[2] + red2[3]);
    const float scale = 1.0f / (8.0f * fmaxf(nrm, 1e-12f));

    float* outr = out + ((size_t)b * K_ + k) * D_;
    outr[tid]       = v0 * scale;
    outr[tid + 256] = v1 * scale;
}

extern "C" void kernel_launch(void* const* d_in, const int* in_sizes, int n_in,
                              void* d_out, int out_size, void* d_ws, size_t ws_size,
                              hipStream_t stream) {
    const float* x       = (const float*)d_in[0];
    const float* conv_w  = (const float*)d_in[1];
    const float* conv_b  = (const float*)d_in[2];
    const float* centers = (const float*)d_in[3];
    float* out = (float*)d_out;

    char* wsb = (char*)d_ws;
    float* vlad            = (float*)wsb;                          // 2 MiB
    float* wsumbuf         = (float*)(wsb + (2u << 20));           // 4 KiB
    unsigned short* wh     = (unsigned short*)(wsb + (3u << 20));  // 8 MiB
    unsigned short* wl     = (unsigned short*)(wsb + (11u << 20)); // 8 MiB
    unsigned short* cwL    = (unsigned short*)(wsb + (19u << 20)); // 192 KiB

    // zero vlad (2 MiB) + wsumbuf (4 KiB) in one memset
    hipMemsetAsync(vlad, 0, (2u << 20) + 4096, stream);

    k_prep<<<32, 256, 0, stream>>>(conv_w, cwL);
    k_logits_softmax<<<B_ * 64, 256, 0, stream>>>(x, cwL, conv_b, wh, wl, wsumbuf);
    k_wx<<<B_ * 4 * 16, 256, 0, stream>>>(x, wh, wl, vlad);
    k_norm<<<B_ * K_, 256, 0, stream>>>(wsumbuf, vlad, centers, out);
}

// Round 6
// 237.364 us; speedup vs baseline: 1.1190x; 1.1190x over previous
//
#include <hip/hip_runtime.h>
#include <hip/hip_bf16.h>
#include <math.h>

#define B_ 16
#define D_ 512
#define N_ 4096   // H*W
#define K_ 64

typedef __attribute__((ext_vector_type(8))) short bfrag;   // 8 bf16 = 4 VGPRs
typedef __attribute__((ext_vector_type(4))) float f32x4;

static __device__ __forceinline__ float bf2f(unsigned short u) {
    return __uint_as_float(((unsigned)u) << 16);
}
static __device__ __forceinline__ unsigned short f2bf(float v) {
    __hip_bfloat16 h = __float2bfloat16(v);   // RNE
    union { __hip_bfloat16 h; unsigned short u; } cv; cv.h = h; return cv.u;
}
static __device__ __forceinline__ void split3(float v, unsigned short& h,
                                              unsigned short& m, unsigned short& l) {
    h = f2bf(v); float r1 = v - bf2f(h);
    m = f2bf(r1); float r2 = r1 - bf2f(m);
    l = f2bf(r2);
}
static __device__ __forceinline__ void split2(float v, unsigned short& h,
                                              unsigned short& l) {
    h = f2bf(v); l = f2bf(v - bf2f(h));
}
#define MFMA(a, b, c) __builtin_amdgcn_mfma_f32_16x16x32_bf16((a), (b), (c), 0, 0, 0)

// ---------------------------------------------------------------------------
// K0: pre-split conv_w into 3 bf16 limb planes [lv][64][512] (192 KB total).
// ---------------------------------------------------------------------------
__global__ __launch_bounds__(256) void k_prep(
    const float* __restrict__ conv_w, unsigned short* __restrict__ cwL)
{
    const int i = blockIdx.x * 256 + threadIdx.x;
    const float4 v = *(const float4*)&conv_w[i * 4];
    const float vv[4] = {v.x, v.y, v.z, v.w};
    unsigned short h[4], m[4], l[4];
    #pragma unroll
    for (int j = 0; j < 4; ++j) split3(vv[j], h[j], m[j], l[j]);
    *(ushort4*)&cwL[0 * (K_ * D_) + i * 4] = make_ushort4(h[0], h[1], h[2], h[3]);
    *(ushort4*)&cwL[1 * (K_ * D_) + i * 4] = make_ushort4(m[0], m[1], m[2], m[3]);
    *(ushort4*)&cwL[2 * (K_ * D_) + i * 4] = make_ushort4(l[0], l[1], l[2], l[3]);
}

// ---------------------------------------------------------------------------
// K1: logits via 3-way-split bf16 MFMA + softmax + w limbs + fused wsum.
// r3 geometry (128n tile, grid 512 — best measured). xs uses a 16B-chunk XOR
// swizzle C^=(row>>3)&3: staging writes drop from 8-way conflicts to 2-way,
// fragment b128 reads become conflict-free (r5 counter: 6.29M conflict cyc).
// ---------------------------------------------------------------------------
__global__ __launch_bounds__(256) void k_logits_softmax(
    const float* __restrict__ x, const unsigned short* __restrict__ cwL,
    const float* __restrict__ conv_b,
    unsigned short* __restrict__ wh, unsigned short* __restrict__ wl,
    float* __restrict__ wsumbuf)
{
    const int b   = blockIdx.x >> 5;
    const int n0  = (blockIdx.x & 31) * 128;
    const int tid  = threadIdx.x;
    const int w    = tid >> 6;
    const int lane = tid & 63;
    const int q = lane >> 4;
    const int c = lane & 15;
    const int ktb = (w & 1) * 32;
    const int ntb = (w >> 1) * 64;

    __shared__ unsigned short cws[3][64][40];   // [lvl][k][d]
    __shared__ unsigned short xs[3][128][40];   // [lvl][n][d-swizzled]
    __shared__ float redm[2][128];
    __shared__ float reds[2][128];

    f32x4 acc[2][4];
    #pragma unroll
    for (int kt = 0; kt < 2; ++kt)
        #pragma unroll
        for (int nt = 0; nt < 4; ++nt) acc[kt][nt] = (f32x4){0.f, 0.f, 0.f, 0.f};

    const float* xb = x + (size_t)b * D_ * N_ + n0;

    const int ks = tid >> 2;            // cw row
    const int d8 = (tid & 3) * 8;       // cw d-offset

    for (int d0 = 0; d0 < D_; d0 += 32) {
        // stage cw limbs: raw uint4 copies from pre-split planes
        #pragma unroll
        for (int lv = 0; lv < 3; ++lv)
            *(uint4*)&cws[lv][ks][d8] =
                *(const uint4*)&cwL[lv * (K_ * D_) + ks * D_ + d0 + d8];
        // stage x 32d x 128n transposed -> xs[n][d], split3, swizzled chunks
        #pragma unroll
        for (int i = 0; i < 4; ++i) {
            const int s  = i * 256 + tid;
            const int xn = s & 127;
            const int j  = s >> 7;                      // 8B chunk 0..7
            const int Cs = ((j >> 1) ^ ((xn >> 3) & 3)); // swizzled 16B chunk
            const int dsw = (Cs * 2 + (j & 1)) * 4;      // swizzled short offset
            const int dg4 = j * 4;                       // source d offset
            unsigned short h[4], m[4], l[4];
            #pragma unroll
            for (int r = 0; r < 4; ++r) {
                const float v = xb[(size_t)(d0 + dg4 + r) * N_ + xn];
                split3(v, h[r], m[r], l[r]);
            }
            *(ushort4*)&xs[0][xn][dsw] = make_ushort4(h[0], h[1], h[2], h[3]);
            *(ushort4*)&xs[1][xn][dsw] = make_ushort4(m[0], m[1], m[2], m[3]);
            *(ushort4*)&xs[2][xn][dsw] = make_ushort4(l[0], l[1], l[2], l[3]);
        }
        __syncthreads();

        bfrag af[2][3];
        #pragma unroll
        for (int kt = 0; kt < 2; ++kt)
            #pragma unroll
            for (int lv = 0; lv < 3; ++lv)
                af[kt][lv] = *(const bfrag*)&cws[lv][ktb + kt * 16 + c][q * 8];
        #pragma unroll
        for (int nt = 0; nt < 4; ++nt) {
            const int row = ntb + nt * 16 + c;
            const int qs  = (q ^ ((row >> 3) & 3)) * 8;  // swizzled read chunk
            bfrag bf[3];
            #pragma unroll
            for (int lv = 0; lv < 3; ++lv)
                bf[lv] = *(const bfrag*)&xs[lv][row][qs];
            #pragma unroll
            for (int kt = 0; kt < 2; ++kt) {
                f32x4 a = acc[kt][nt];
                a = MFMA(af[kt][0], bf[0], a);   // hh
                a = MFMA(af[kt][0], bf[1], a);   // hm
                a = MFMA(af[kt][1], bf[0], a);   // mh
                a = MFMA(af[kt][1], bf[1], a);   // mm
                a = MFMA(af[kt][0], bf[2], a);   // hl
                a = MFMA(af[kt][2], bf[0], a);   // lh
                acc[kt][nt] = a;
            }
        }
        __syncthreads();
    }

    // ---- bias + cross-wave softmax (lane owns k=ktb+kt*16+q*4+r, n=ntb+nt*16+c)
    #pragma unroll
    for (int kt = 0; kt < 2; ++kt)
        #pragma unroll
        for (int r = 0; r < 4; ++r) {
            const float bias = conv_b[ktb + kt * 16 + q * 4 + r];
            #pragma unroll
            for (int nt = 0; nt < 4; ++nt) acc[kt][nt][r] += bias;
        }

    float mloc[4];
    #pragma unroll
    for (int nt = 0; nt < 4; ++nt) {
        float m = acc[0][nt][0];
        #pragma unroll
        for (int kt = 0; kt < 2; ++kt)
            #pragma unroll
            for (int r = 0; r < 4; ++r) m = fmaxf(m, acc[kt][nt][r]);
        m = fmaxf(m, __shfl_xor(m, 16));
        m = fmaxf(m, __shfl_xor(m, 32));
        mloc[nt] = m;
    }
    if (q == 0)
        #pragma unroll
        for (int nt = 0; nt < 4; ++nt) redm[w & 1][ntb + nt * 16 + c] = mloc[nt];
    __syncthreads();
    float mall[4];
    #pragma unroll
    for (int nt = 0; nt < 4; ++nt)
        mall[nt] = fmaxf(redm[0][ntb + nt * 16 + c], redm[1][ntb + nt * 16 + c]);

    float sloc[4] = {0.f, 0.f, 0.f, 0.f};
    #pragma unroll
    for (int nt = 0; nt < 4; ++nt) {
        #pragma unroll
        for (int kt = 0; kt < 2; ++kt)
            #pragma unroll
            for (int r = 0; r < 4; ++r) {
                const float e = __expf(acc[kt][nt][r] - mall[nt]);
                acc[kt][nt][r] = e;
                sloc[nt] += e;
            }
        sloc[nt] += __shfl_xor(sloc[nt], 16);
        sloc[nt] += __shfl_xor(sloc[nt], 32);
    }
    if (q == 0)
        #pragma unroll
        for (int nt = 0; nt < 4; ++nt) reds[w & 1][ntb + nt * 16 + c] = sloc[nt];
    __syncthreads();

    float wacc[2][4] = {{0.f, 0.f, 0.f, 0.f}, {0.f, 0.f, 0.f, 0.f}};
    #pragma unroll
    for (int nt = 0; nt < 4; ++nt) {
        const float inv = 1.0f / (reds[0][ntb + nt * 16 + c] + reds[1][ntb + nt * 16 + c]);
        #pragma unroll
        for (int kt = 0; kt < 2; ++kt)
            #pragma unroll
            for (int r = 0; r < 4; ++r) {
                const float v = acc[kt][nt][r] * inv;
                unsigned short hi, lo;
                split2(v, hi, lo);
                const size_t idx = ((size_t)b * K_ + ktb + kt * 16 + q * 4 + r) * N_
                                 + n0 + ntb + nt * 16 + c;
                wh[idx] = hi;
                wl[idx] = lo;
                wacc[kt][r] += v;
            }
    }
    // fused wsum: reduce over the 16 c-lanes, then one atomic per (k, wave)
    #pragma unroll
    for (int msk = 1; msk < 16; msk <<= 1)
        #pragma unroll
        for (int kt = 0; kt < 2; ++kt)
            #pragma unroll
            for (int r = 0; r < 4; ++r)
                wacc[kt][r] += __shfl_xor(wacc[kt][r], msk);
    if (c == 0)
        #pragma unroll
        for (int kt = 0; kt < 2; ++kt)
            #pragma unroll
            for (int r = 0; r < 4; ++r)
                atomicAdd(&wsumbuf[b * K_ + ktb + kt * 16 + q * 4 + r], wacc[kt][r]);
}

// ---------------------------------------------------------------------------
// K2: vlad += w . x^T via 2-way-split bf16 MFMA. r3 geometry (nc=8, grid 512
// — best measured; r5's nc=16 split regressed). Staging writes ~2-way (ok),
// fragment reads 2-way (free) — no swizzle needed here.
// ---------------------------------------------------------------------------
__global__ __launch_bounds__(256) void k_wx(
    const float* __restrict__ x, const unsigned short* __restrict__ wh,
    const unsigned short* __restrict__ wl, float* __restrict__ vlad)
{
    const int nc = blockIdx.x & 7;
    const int dc = (blockIdx.x >> 3) & 3;
    const int b  = blockIdx.x >> 5;
    const int tid  = threadIdx.x;
    const int w    = tid >> 6;
    const int lane = tid & 63;
    const int q = lane >> 4;
    const int c = lane & 15;
    const int ktb = (w & 1) * 32;
    const int dtb = (w >> 1) * 64;

    __shared__ unsigned short ws2[2][64][40];    // [lvl][k][n]
    __shared__ unsigned short xs2[2][128][40];   // [lvl][d][n]

    f32x4 acc[2][4];
    #pragma unroll
    for (int kt = 0; kt < 2; ++kt)
        #pragma unroll
        for (int dt = 0; dt < 4; ++dt) acc[kt][dt] = (f32x4){0.f, 0.f, 0.f, 0.f};

    const float* xb = x + (size_t)b * D_ * N_ + (size_t)dc * 128 * N_;
    const unsigned short* whb = wh + (size_t)b * K_ * N_;
    const unsigned short* wlb = wl + (size_t)b * K_ * N_;

    const int wk = tid >> 2;            // w row
    const int wn = (tid & 3) * 8;       // w n-offset
    const int xd = tid >> 3;            // x row (i adds 32i)
    const int xn = (tid & 7) * 4;       // x n-offset

    const int nbase = nc * 512;
    for (int n0 = nbase; n0 < nbase + 512; n0 += 32) {
        *(uint4*)&ws2[0][wk][wn] = *(const uint4*)&whb[(size_t)wk * N_ + n0 + wn];
        *(uint4*)&ws2[1][wk][wn] = *(const uint4*)&wlb[(size_t)wk * N_ + n0 + wn];
        #pragma unroll
        for (int i = 0; i < 4; ++i) {
            const float4 v = *(const float4*)&xb[(size_t)(i * 32 + xd) * N_ + n0 + xn];
            const float vv[4] = {v.x, v.y, v.z, v.w};
            unsigned short h[4], l[4];
            #pragma unroll
            for (int j = 0; j < 4; ++j) split2(vv[j], h[j], l[j]);
            *(ushort4*)&xs2[0][i * 32 + xd][xn] = make_ushort4(h[0], h[1], h[2], h[3]);
            *(ushort4*)&xs2[1][i * 32 + xd][xn] = make_ushort4(l[0], l[1], l[2], l[3]);
        }
        __syncthreads();

        bfrag afh[2], afl[2];
        #pragma unroll
        for (int kt = 0; kt < 2; ++kt) {
            afh[kt] = *(const bfrag*)&ws2[0][ktb + kt * 16 + c][q * 8];
            afl[kt] = *(const bfrag*)&ws2[1][ktb + kt * 16 + c][q * 8];
        }
        #pragma unroll
        for (int dt = 0; dt < 4; ++dt) {
            const bfrag bh = *(const bfrag*)&xs2[0][dtb + dt * 16 + c][q * 8];
            const bfrag bl = *(const bfrag*)&xs2[1][dtb + dt * 16 + c][q * 8];
            #pragma unroll
            for (int kt = 0; kt < 2; ++kt) {
                f32x4 a = acc[kt][dt];
                a = MFMA(afh[kt], bh, a);
                a = MFMA(afh[kt], bl, a);
                a = MFMA(afl[kt], bh, a);
                acc[kt][dt] = a;
            }
        }
        __syncthreads();
    }

    #pragma unroll
    for (int kt = 0; kt < 2; ++kt)
        #pragma unroll
        for (int dt = 0; dt < 4; ++dt)
            #pragma unroll
            for (int r = 0; r < 4; ++r) {
                const int k = ktb + kt * 16 + q * 4 + r;
                const int d = dc * 128 + dtb + dt * 16 + c;
                atomicAdd(&vlad[((size_t)b * K_ + k) * D_ + d], acc[kt][dt][r]);
            }
}

// ---------------------------------------------------------------------------
// K3: v = vlad - wsum*c; row L2-norm; global norm = /8.  (wsum precomputed)
// ---------------------------------------------------------------------------
__global__ __launch_bounds__(256) void k_norm(
    const float* __restrict__ wsumbuf, const float* __restrict__ vlad,
    const float* __restrict__ centers, float* __restrict__ out)
{
    const int b = blockIdx.x >> 6;
    const int k = blockIdx.x & 63;
    const int tid = threadIdx.x;

    const float wsum = wsumbuf[b * K_ + k];

    const float* vr = vlad + ((size_t)b * K_ + k) * D_;
    const float* cr = centers + k * D_;
    const float v0 = vr[tid]       - wsum * cr[tid];
    const float v1 = vr[tid + 256] - wsum * cr[tid + 256];

    float ss = v0 * v0 + v1 * v1;
    __shared__ float red2[4];
    #pragma unroll
    for (int off = 32; off > 0; off >>= 1) ss += __shfl_down(ss, off, 64);
    if ((tid & 63) == 0) red2[tid >> 6] = ss;
    __syncthreads();
    const float nrm = sqrtf(red2[0] + red2[1] + red2[2] + red2[3]);
    const float scale = 1.0f / (8.0f * fmaxf(nrm, 1e-12f));

    float* outr = out + ((size_t)b * K_ + k) * D_;
    outr[tid]       = v0 * scale;
    outr[tid + 256] = v1 * scale;
}

extern "C" void kernel_launch(void* const* d_in, const int* in_sizes, int n_in,
                              void* d_out, int out_size, void* d_ws, size_t ws_size,
                              hipStream_t stream) {
    const float* x       = (const float*)d_in[0];
    const float* conv_w  = (const float*)d_in[1];
    const float* conv_b  = (const float*)d_in[2];
    const float* centers = (const float*)d_in[3];
    float* out = (float*)d_out;

    char* wsb = (char*)d_ws;
    float* vlad            = (float*)wsb;                          // 2 MiB
    float* wsumbuf         = (float*)(wsb + (2u << 20));           // 4 KiB
    unsigned short* wh     = (unsigned short*)(wsb + (3u << 20));  // 8 MiB
    unsigned short* wl     = (unsigned short*)(wsb + (11u << 20)); // 8 MiB
    unsigned short* cwL    = (unsigned short*)(wsb + (19u << 20)); // 192 KiB

    hipMemsetAsync(vlad, 0, (2u << 20) + 4096, stream);

    k_prep<<<32, 256, 0, stream>>>(conv_w, cwL);
    k_logits_softmax<<<B_ * 32, 256, 0, stream>>>(x, cwL, conv_b, wh, wl, wsumbuf);
    k_wx<<<B_ * 4 * 8, 256, 0, stream>>>(x, wh, wl, vlad);
    k_norm<<<B_ * K_, 256, 0, stream>>>(wsumbuf, vlad, centers, out);
}